// Round 5
// baseline (306.636 us; speedup 1.0000x reference)
//
#include <hip/hip_runtime.h>
#include <math.h>

#define NB 16
#define NC 8
#define HH 512
#define WW 512
#define HW (HH * WW)
#define CHW (NC * HW)
#define NSEG 8   // 64-px segments per 512-px row-pair, one row-pair per wave

typedef const __attribute__((address_space(1))) void* gvp;
typedef __attribute__((address_space(3))) void*       lvp;

// t is exactly 0.0/1.0: BCE elem = -max(log(t ? p : 1-p), -100)
__device__ __forceinline__ float bce_term(float t, float p) {
    float q = (t > 0.5f) ? p : (1.0f - p);
    return -fmaxf(__logf(q), -100.0f);
}

// Wave-private pipeline: each wave sweeps one row-pair (2 x 512 px) in 8
// tiles of 64x2 px. Per tile: 6 global_load_lds stage 24 planes (22 c_map
// channel-rows + 2 target rows) into a wave-private LDS double buffer; a
// manual s_waitcnt vmcnt(6) waits for tile t while tile t+1's DMA stays in
// flight. NO __syncthreads in the loop -> no vmcnt(0) barrier drain (the
// R4 killer). w-shifts are in-register __shfl; segment-edge columns come
// from one lane-distributed global load broadcast via __shfl.
__global__ __launch_bounds__(256) void bicon_loss_kernel(
    const float* __restrict__ c_map,
    const float* __restrict__ target,
    const float* __restrict__ con_target,
    float* __restrict__ out)
{
    // per wave: [2 bufs][24 planes][64 cols]  (12 KB) -> 48 KB/block, 3 blocks/CU
    __shared__ float buf[4][2][24][64];
    __shared__ float wsum[4];

    const int tid  = threadIdx.x;
    const int wave = tid >> 6;
    const int lane = tid & 63;
    const int wid  = blockIdx.x * 4 + wave;   // 4096 waves
    const int b    = wid >> 8;
    const int h0   = (wid & 255) << 1;        // row-pair base

    // ---- per-wave DMA lane pointers: instr s covers planes 4s..4s+3,
    // lanes (s*4 + lane>>4) pick the plane, (lane&15)*16B the column slice.
    // planes 0-2: row h0-1 ch{5,6,7}; 3-10: row h0 ch0-7; 11-18: row h0+1
    // ch0-7; 19-21: row h0+2 ch{0,1,2}; 22,23: target rows h0,h0+1.
    const float* dma_ptr[6];
    #pragma unroll
    for (int s = 0; s < 6; ++s) {
        const int pp = s * 4 + (lane >> 4);
        const float* base;
        if (pp < 22) {
            int ch, rel;
            if (pp < 3)       { ch = 5 + pp;  rel = -1; }
            else if (pp < 11) { ch = pp - 3;  rel = 0;  }
            else if (pp < 19) { ch = pp - 11; rel = 1;  }
            else              { ch = pp - 19; rel = 2;  }
            int rr = h0 + rel; rr = rr < 0 ? 0 : (rr > HH - 1 ? HH - 1 : rr);
            base = c_map + b * CHW + ch * HW + rr * WW;
        } else {
            base = target + b * HW + (h0 + pp - 22) * WW;
        }
        dma_ptr[s] = base + (lane & 15) * 4;
    }

    // ---- per-wave edge pointer: lane k<12 loads edge value k =
    // (ch,relrow,col) needed by lane0/lane63 shifts. Packed tables (nibbles):
    //  k even -> col w0+64 (R), k odd -> col w0-1 (L); kk = k>>1:
    //  chR = {5,3,2,3,5,2}, chL = {7,4,0,4,7,0}, rel+1 = {0,1,2,2,1,3}
    {
    }
    const int k    = lane < 12 ? lane : 0;
    const int kk4  = (k >> 1) * 4;
    const int dirR = ((k & 1) == 0);
    const int ch_e = dirR ? ((0x253235 >> kk4) & 15) : ((0x074047 >> kk4) & 15);
    const int rel_e = ((0x312210 >> kk4) & 15) - 1;
    int rre = h0 + rel_e; rre = rre < 0 ? 0 : (rre > HH - 1 ? HH - 1 : rre);
    const float* eptr = c_map + b * CHW + ch_e * HW + rre * WW + (dirR ? 64 : -1);

    float (*mybuf)[24][64] = buf[wave];

    // ---- prologue: stage tile 0, load edge 0 ----
    #pragma unroll
    for (int s = 0; s < 6; ++s)
        __builtin_amdgcn_global_load_lds((gvp)dma_ptr[s], (lvp)&mybuf[0][s * 4][0], 16, 0, 0);
    float ex_cur = eptr[0];

    const bool hu  = (h0 > 0);        // row h's up-row validity (uniform)
    const bool hd2 = (h0 < HH - 2);   // row h+1's down-row validity (uniform)

    float acc_con = 0.0f, acc_bi = 0.0f, acc_de = 0.0f;

    for (int t = 0; t < NSEG; ++t) {
        const int par = t & 1;
        if (t + 1 < NSEG) {
            const int w1 = (t + 1) << 6;
            #pragma unroll
            for (int s = 0; s < 6; ++s)
                __builtin_amdgcn_global_load_lds((gvp)(dma_ptr[s] + w1),
                                                 (lvp)&mybuf[(t + 1) & 1][s * 4][0], 16, 0, 0);
            __builtin_amdgcn_s_waitcnt(0x0F76);   // vmcnt(6): tile t drained, t+1 in flight
        } else {
            __builtin_amdgcn_s_waitcnt(0x0F70);   // vmcnt(0): last tile, drain all
        }
        asm volatile("" ::: "memory");            // fence IR reordering of LDS reads

        const int w0 = t << 6;
        const int gw = w0 + lane;
        const bool wl = (gw > 0), wr = (gw < WW - 1);

        // con_target loads for this tile (issued early, consumed late)
        const float* ctb = con_target + b * CHW + h0 * WW + gw;
        float tv0[8], tv1[8];
        #pragma unroll
        for (int c = 0; c < 8; ++c) { tv0[c] = ctb[c * HW]; tv1[c] = ctb[c * HW + WW]; }
        float ex_next = 0.0f;
        if (t + 1 < NSEG) ex_next = eptr[(t + 1) << 6];

        // LDS -> x -> u = 1 + exp(-x)   (sigmoid p = 1/u)
        float u[22], xc[16];
        #pragma unroll
        for (int pp = 0; pp < 22; ++pp) {
            const float x = mybuf[par][pp][lane];
            if (pp >= 3 && pp < 19) xc[pp - 3] = x;
            u[pp] = 1.0f + __expf(-x);
        }
        const float tg0 = mybuf[par][22][lane];
        const float tg1 = mybuf[par][23][lane];
        const float ue  = 1.0f + __expf(-ex_cur);

        #define U0(c) u[3 + (c)]
        #define U1(c) u[11 + (c)]
        auto SHP = [&](float v, int ek) -> float {   // u at column w+1
            float s = __shfl(v, (lane + 1) & 63, 64);
            float e = __shfl(ue, ek, 64);
            return (lane == 63) ? e : s;
        };
        auto SHM = [&](float v, int ek) -> float {   // u at column w-1
            float s = __shfl(v, (lane + 63) & 63, 64);
            float e = __shfl(ue, ek, 64);
            return (lane == 0) ? e : s;
        };
        auto VOTE = [&](float uc, float un, bool valid) -> float {
            return valid ? __fdividef(1.0f, uc * un) : 0.0f;
        };

        // ---- row h votes (R4-verified neighbor semantics) ----
        const float m4  = SHM(U0(4), 3);
        const float m3  = SHP(U0(3), 2);
        const float n5  = SHP(u[0], 0);
        const float n6  = u[1];
        const float n7  = SHM(u[2], 1);
        const float dn1 = U1(1);
        const float dn2 = SHP(U1(2), 4);
        const float dn0 = SHM(U1(0), 5);
        const float a1 = VOTE(U0(3), m4, wl);
        const float a2 = VOTE(U0(4), m3, wr);
        const float a3 = VOTE(U0(1), n6, hu);
        const float a4 = VOTE(U0(6), dn1, true);
        const float a5 = VOTE(U0(2), n5, hu && wr);
        const float a6 = VOTE(U0(5), dn2, wr);
        const float a7 = VOTE(U0(0), n7, hu && wl);
        const float a8 = VOTE(U0(7), dn0, wl);

        // ---- row h+1 votes ----
        const float m4b  = SHM(U1(4), 7);
        const float m3b  = SHP(U1(3), 6);
        const float n5b  = SHP(U0(5), 8);
        const float n6b  = U0(6);
        const float n7b  = SHM(U0(7), 9);
        const float dn1b = u[20];
        const float dn2b = SHP(u[21], 10);
        const float dn0b = SHM(u[19], 11);
        const float b1 = VOTE(U1(3), m4b, wl);
        const float b2 = VOTE(U1(4), m3b, wr);
        const float b3 = VOTE(U1(1), n6b, true);
        const float b4 = VOTE(U1(6), dn1b, hd2);
        const float b5 = VOTE(U1(2), n5b, wr);
        const float b6 = VOTE(U1(5), dn2b, hd2 && wr);
        const float b7 = VOTE(U1(0), n7b, wl);
        const float b8 = VOTE(U1(7), dn0b, hd2 && wl);

        // ---- conmap: bce(t, 1/u) = log(u) + (1-t)*x  (clip inert, |x|<~6) ----
        #pragma unroll
        for (int c = 0; c < 8; ++c) {
            acc_con += __logf(u[3 + c])  + (tv0[c] > 0.5f ? 0.0f : xc[c]);
            acc_con += __logf(u[11 + c]) + (tv1[c] > 0.5f ? 0.0f : xc[8 + c]);
        }

        // ---- bimap + de (stack order [a7,a3,a5,a1,a2,a6,a4,a8]) ----
        const float v0[8] = { a7, a3, a5, a1, a2, a6, a4, a8 };
        const float v1[8] = { b7, b3, b5, b1, b2, b6, b4, b8 };
        float sc0 = 0.0f, sc1 = 0.0f;
        #pragma unroll
        for (int c = 0; c < 8; ++c) { sc0 += tv0[c]; sc1 += tv1[c]; }
        #pragma unroll
        for (int c = 0; c < 8; ++c) {
            acc_bi += bce_term(tv0[c], v0[c]);
            acc_bi += bce_term(tv1[c], v1[c]);
        }
        const float g0 = (a1 + a2 + a3 + a4 + a5 + a6 + a7 + a8) * 0.125f;
        const float g1 = (b1 + b2 + b3 + b4 + b5 + b6 + b7 + b8) * 0.125f;
        float mn0 = v0[0], mn1 = v1[0];
        #pragma unroll
        for (int c = 1; c < 8; ++c) { mn0 = fminf(mn0, v0[c]); mn1 = fminf(mn1, v1[c]); }
        const bool  e0 = (sc0 < 8.0f) && (sc0 > 0.0f);
        const bool  e1 = (sc1 < 8.0f) && (sc1 > 0.0f);
        const float d0 = e0 ? (1.0f - mn0) : g0;
        const float d1 = e1 ? (1.0f - mn1) : g1;
        acc_de += bce_term(tg0, d0);
        acc_de += bce_term(tg1, d1);

        ex_cur = ex_next;
        #undef U0
        #undef U1
    }

    // ---- reduction: wave shuffle -> LDS -> one atomic per block ----
    float local = fmaf(0.8f, acc_con, fmaf(0.2f, acc_bi, acc_de));
    #pragma unroll
    for (int off = 32; off > 0; off >>= 1)
        local += __shfl_down(local, off, 64);
    if (lane == 0) wsum[wave] = local;
    __syncthreads();
    if (tid == 0) atomicAdd(out, wsum[0] + wsum[1] + wsum[2] + wsum[3]);
}

extern "C" void kernel_launch(void* const* d_in, const int* in_sizes, int n_in,
                              void* d_out, int out_size, void* d_ws, size_t ws_size,
                              hipStream_t stream) {
    const float* c_map      = (const float*)d_in[0];
    const float* target     = (const float*)d_in[1];
    const float* con_target = (const float*)d_in[2];
    float* out = (float*)d_out;

    hipMemsetAsync(out, 0, sizeof(float), stream);

    const int blocks = (NB * (HH / 2)) / 4;   // 4096 waves / 4 per block = 1024
    bicon_loss_kernel<<<blocks, 256, 0, stream>>>(c_map, target, con_target, out);
}